// Round 11
// baseline (133.051 us; speedup 1.0000x reference)
//
#include <hip/hip_runtime.h>
#include <hip/hip_bf16.h>

typedef _Float16 h2 __attribute__((ext_vector_type(2)));
typedef _Float16 h8 __attribute__((ext_vector_type(8)));
typedef __attribute__((ext_vector_type(8))) unsigned short ushort8v;
typedef __attribute__((ext_vector_type(4))) float f32x4;

__device__ __forceinline__ unsigned short f2h_bits(float f) {
    union { _Float16 h; unsigned short u; } v;
    v.h = (_Float16)f;
    return v.u;
}

// prep: blocks [0,64)          -> W1/W2 permute to MFMA-fragment-linear fp16
//       blocks [64,64+nxb)     -> x (f32) -> xh (fp16), 8 elems/thread
//       blocks [64+nxb, ...)   -> degree histogram into offs + rank[e]
__global__ __launch_bounds__(256) void prep_kernel(
    const float* __restrict__ W1, const float* __restrict__ W2,
    const float* __restrict__ x, const int* __restrict__ dst,
    unsigned short* __restrict__ wtf1, unsigned short* __restrict__ wtf2,
    unsigned short* __restrict__ xh, int* __restrict__ offs,
    int* __restrict__ rank, int n8, int E, int nxb)
{
    int bid = blockIdx.x;
    if (bid < 64) {
        int t = bid * 256 + threadIdx.x;   // 0..16383
        int k = t >> 7, j = t & 127;
        int jt = j >> 4, r = j & 15, kt = k >> 5, kg = (k >> 3) & 3, e = k & 7;
        int flin = (jt * 4 + kt) * 512 + (kg * 16 + r) * 8 + e;
        wtf1[flin] = f2h_bits(W1[t]);
        wtf2[flin] = f2h_bits(W2[t]);
        return;
    }
    if (bid < 64 + nxb) {
        int t = (bid - 64) * 256 + threadIdx.x;
        if (t >= n8) return;
        float4 x0 = reinterpret_cast<const float4*>(x)[(size_t)t * 2];
        float4 x1 = reinterpret_cast<const float4*>(x)[(size_t)t * 2 + 1];
        ushort8v o;
        o[0] = f2h_bits(x0.x); o[1] = f2h_bits(x0.y);
        o[2] = f2h_bits(x0.z); o[3] = f2h_bits(x0.w);
        o[4] = f2h_bits(x1.x); o[5] = f2h_bits(x1.y);
        o[6] = f2h_bits(x1.z); o[7] = f2h_bits(x1.w);
        reinterpret_cast<ushort8v*>(xh)[t] = o;
        return;
    }
    int e = (bid - 64 - nxb) * 256 + threadIdx.x;
    if (e < E) rank[e] = atomicAdd(&offs[dst[e]], 1);
}

// Per-1024-chunk exclusive scan in place; LAST finishing block scans chunk sums.
__global__ __launch_bounds__(256) void scan_kernel(
    int* __restrict__ offs, int* __restrict__ bsums, int* __restrict__ done,
    int N, int nchunk)
{
    __shared__ int tsum[256];
    __shared__ int amLast;
    int c = blockIdx.x, tid = threadIdx.x;
    int base = c * 1024 + tid * 4;
    int v[4]; int tl = 0;
    #pragma unroll
    for (int j = 0; j < 4; ++j) {
        v[j] = (base + j < N) ? offs[base + j] : 0;
        tl += v[j];
    }
    tsum[tid] = tl; __syncthreads();
    for (int off = 1; off < 256; off <<= 1) {
        int u = (tid >= off) ? tsum[tid - off] : 0;
        __syncthreads();
        tsum[tid] += u;
        __syncthreads();
    }
    int run = tsum[tid] - tl;   // exclusive within chunk
    #pragma unroll
    for (int j = 0; j < 4; ++j) {
        if (base + j < N) offs[base + j] = run;
        run += v[j];
    }
    if (tid == 255) {
        __hip_atomic_store(&bsums[c], tsum[255], __ATOMIC_RELEASE,
                           __HIP_MEMORY_SCOPE_AGENT);
        int prev = __hip_atomic_fetch_add(done, 1, __ATOMIC_ACQ_REL,
                                          __HIP_MEMORY_SCOPE_AGENT);
        amLast = (prev == nchunk - 1);
    }
    __syncthreads();
    if (amLast) {
        int bv = (tid < nchunk)
            ? __hip_atomic_load(&bsums[tid], __ATOMIC_ACQUIRE,
                                __HIP_MEMORY_SCOPE_AGENT) : 0;
        tsum[tid] = bv; __syncthreads();
        for (int off = 1; off < 256; off <<= 1) {
            int u = (tid >= off) ? tsum[tid - off] : 0;
            __syncthreads();
            tsum[tid] += u;
            __syncthreads();
        }
        if (tid < nchunk)
            __hip_atomic_store(&bsums[tid], tsum[tid] - bv, __ATOMIC_RELEASE,
                               __HIP_MEMORY_SCOPE_AGENT);
    }
}

// Scatter (src, {w,w} fp16-pair) into CSR slot offs[d]+bsums+rank — NO atomic.
__global__ __launch_bounds__(256) void scatter_kernel(
    const int* __restrict__ src, const int* __restrict__ dst,
    const float* __restrict__ ew, const int* __restrict__ offs,
    const int* __restrict__ bsums, const int* __restrict__ rank,
    int2* __restrict__ esrt, int E)
{
    int e = blockIdx.x * 256 + threadIdx.x;
    if (e >= E) return;
    int d = dst[e];
    int pos = offs[d] + bsums[d >> 10] + rank[e];
    _Float16 wh = (_Float16)ew[e];
    union { h2 h; int i; } uw; uw.h = (h2){wh, wh};
    esrt[pos] = make_int2(src[e], uw.i);
}

// ---- Fused: CSR gather -> LDS -> 2x f16 MFMA. 128 thr / 32 nodes / 8KB LDS:
// small blocks double resident blocks/CU during the latency-bound gather.
__global__ __launch_bounds__(128, 8) void fused_kernel(
    const unsigned short* __restrict__ xh, const int* __restrict__ offs,
    const int* __restrict__ bsums, const int2* __restrict__ esrt,
    const unsigned short* __restrict__ wtf1,
    const unsigned short* __restrict__ wtf2,
    const float* __restrict__ b1, const float* __restrict__ b2,
    float* __restrict__ y, int N, int E)
{
    __shared__ __align__(16) unsigned short Hs[32 * 128];
    int tid = threadIdx.x;
    int node0 = blockIdx.x * 32;

    // Phase 1: gather. 8 groups x 16 lanes; group g owns rows {g, 8+g, 16+g, 24+g}.
    // Lane l holds elems 8l..8l+7 (16B -> 256B/row coalesced per broadcast src).
    {
        int g = tid >> 4, l = tid & 15;
        const h8* xr = reinterpret_cast<const h8*>(xh);

        // Prefetch 4 node-streams' CSR ranges, batch-0 metadata, self rows.
        int sA[4], eA[4];
        #pragma unroll
        for (int it = 0; it < 4; ++it) {
            int node = node0 + it * 8 + g;
            int nn = (node < N) ? node : N - 1;
            sA[it] = offs[nn] + bsums[nn >> 10];
            int np = nn + 1;
            eA[it] = (np == N) ? E : offs[np] + bsums[np >> 10];
        }
        int2 evA[4];
        h8 selfA[4];
        #pragma unroll
        for (int it = 0; it < 4; ++it) {
            evA[it] = make_int2(0, 0);
            if (sA[it] + l < eA[it]) evA[it] = esrt[sA[it] + l];
            int node = node0 + it * 8 + g;
            int nn = (node < N) ? node : N - 1;
            selfA[it] = xr[(size_t)nn * 16 + l];
        }

        #pragma unroll
        for (int it = 0; it < 4; ++it) {
            int m = it * 8 + g;
            int node = node0 + m;
            h8 acc = (h8)(_Float16)0;
            if (node < N) {
                acc = selfA[it];                   // self-term (EPS=0)
                int s = sA[it], e = eA[it];
                int2 ev = evA[it];
                for (int base = s; base < e; base += 16) {
                    int cnt = min(e - base, 16);
                    for (int j = 0; j < cnt; j += 8) {
                        h8 v[8]; int wb[8];
                        #pragma unroll
                        for (int q = 0; q < 8; ++q) {
                            int sq = __shfl(ev.x, j + q, 16);
                            wb[q]  = __shfl(ev.y, j + q, 16);
                            v[q] = xr[(size_t)sq * 16 + l];
                        }
                        #pragma unroll
                        for (int q = 0; q < 8; ++q) {
                            union { int4 i; h8 h; } uw;
                            uw.i = make_int4(wb[q], wb[q], wb[q], wb[q]);
                            acc += uw.h * v[q];    // 4x v_pk_fma_f16
                        }
                    }
                    // next batch's metadata (rare: deg > 16)
                    ev = make_int2(0, 0);
                    if (base + 16 + l < e) ev = esrt[base + 16 + l];
                }
            }
            // lane l holds chunk l (8 elems); swizzled chunk slot l ^ (m&7)
            int soff = m * 128 + ((l ^ (m & 7)) << 3);
            *reinterpret_cast<h8*>(&Hs[soff]) = acc;
        }
    }
    __syncthreads();

    int wave = tid >> 6, lane = tid & 63;   // wave in {0,1}
    int r = lane & 15, kg = lane >> 4;
    int row0 = node0 + wave * 16;
    int mr = wave * 16 + r;

    h8 a[4];
    #pragma unroll
    for (int kt = 0; kt < 4; ++kt)
        a[kt] = *reinterpret_cast<const h8*>(
            &Hs[mr * 128 + (((kt * 4 + kg) ^ (r & 7)) << 3)]);

    f32x4 acc1[8];
    #pragma unroll
    for (int jt = 0; jt < 8; ++jt) acc1[jt] = {0.f, 0.f, 0.f, 0.f};

    #pragma unroll
    for (int jt = 0; jt < 8; ++jt) {
        #pragma unroll
        for (int kt = 0; kt < 4; ++kt) {
            h8 b = *reinterpret_cast<const h8*>(
                wtf1 + ((jt * 4 + kt) << 9) + (lane << 3));   // coalesced
            acc1[jt] = __builtin_amdgcn_mfma_f32_16x16x32_f16(a[kt], b, acc1[jt], 0, 0, 0);
        }
    }

    #pragma unroll
    for (int jt = 0; jt < 8; ++jt) {
        float bias = b1[jt * 16 + r];
        int col = jt * 16 + r;
        #pragma unroll
        for (int reg = 0; reg < 4; ++reg) {
            int m2 = wave * 16 + kg * 4 + reg;
            float h = fmaxf(acc1[jt][reg] + bias, 0.0f);
            Hs[m2 * 128 + (((col >> 3) ^ (m2 & 7)) << 3) + (col & 7)] = f2h_bits(h);
        }
    }
    __syncthreads();

    h8 a2[4];
    #pragma unroll
    for (int kt = 0; kt < 4; ++kt)
        a2[kt] = *reinterpret_cast<const h8*>(
            &Hs[mr * 128 + (((kt * 4 + kg) ^ (r & 7)) << 3)]);

    f32x4 acc2[8];
    #pragma unroll
    for (int jt = 0; jt < 8; ++jt) acc2[jt] = {0.f, 0.f, 0.f, 0.f};

    #pragma unroll
    for (int jt = 0; jt < 8; ++jt) {
        #pragma unroll
        for (int kt = 0; kt < 4; ++kt) {
            h8 b = *reinterpret_cast<const h8*>(
                wtf2 + ((jt * 4 + kt) << 9) + (lane << 3));
            acc2[jt] = __builtin_amdgcn_mfma_f32_16x16x32_f16(a2[kt], b, acc2[jt], 0, 0, 0);
        }
    }

    #pragma unroll
    for (int jt = 0; jt < 8; ++jt) {
        float bias = b2[jt * 16 + r];
        #pragma unroll
        for (int reg = 0; reg < 4; ++reg) {
            int orow = row0 + kg * 4 + reg;
            if (orow < N)
                y[(size_t)orow * 128 + jt * 16 + r] = acc2[jt][reg] + bias;
        }
    }
}

extern "C" void kernel_launch(void* const* d_in, const int* in_sizes, int n_in,
                              void* d_out, int out_size, void* d_ws, size_t ws_size,
                              hipStream_t stream) {
    const float* x  = (const float*)d_in[0];
    const int*   ei = (const int*)d_in[1];      // [2,E] as int32
    const float* ew = (const float*)d_in[2];
    const float* W1 = (const float*)d_in[3];
    const float* b1 = (const float*)d_in[4];
    const float* W2 = (const float*)d_in[5];
    const float* b2 = (const float*)d_in[6];
    float* y = (float*)d_out;

    int N = in_sizes[0] / 128;   // 100000
    int E = in_sizes[2];         // 600000
    const size_t ND = (size_t)N * 128;
    int nchunk = (N + 1023) / 1024;   // 98
    int n8 = (int)(ND / 8);
    int nxb = (n8 + 255) / 256;
    int nhist = (E + 255) / 256;

    char* ws = (char*)d_ws;
    size_t off = 0;
    auto bump = [&](size_t bytes) {
        void* p = ws + off;
        off += (bytes + 255) & ~(size_t)255;
        return p;
    };
    // zero-region first (one memset covers offs, done)
    size_t zstart = off;
    int*            offs   = (int*)bump((size_t)N * 4);
    int*            done   = (int*)bump(256);
    size_t zbytes = off - zstart;
    int*            bsums  = (int*)bump(1024);
    int*            rank   = (int*)bump((size_t)E * 4);
    unsigned short* wtf1   = (unsigned short*)bump(128 * 128 * 2);
    unsigned short* wtf2   = (unsigned short*)bump(128 * 128 * 2);
    unsigned short* xh     = (unsigned short*)bump(ND * 2);          // 25.6 MB
    int2*           esrt   = (int2*)bump((size_t)E * 8);

    const int* src = ei;
    const int* dst = ei + E;

    hipMemsetAsync(ws + zstart, 0, zbytes, stream);
    prep_kernel<<<64 + nxb + nhist, 256, 0, stream>>>(
        W1, W2, x, dst, wtf1, wtf2, xh, offs, rank, n8, E, nxb);
    scan_kernel<<<nchunk, 256, 0, stream>>>(offs, bsums, done, N, nchunk);
    scatter_kernel<<<nhist, 256, 0, stream>>>(src, dst, ew, offs, bsums,
                                              rank, esrt, E);
    fused_kernel<<<(N + 31) / 32, 128, 0, stream>>>(
        xh, offs, bsums, esrt, wtf1, wtf2, b1, b2, y, N, E);
}

// Round 12
// 115.011 us; speedup vs baseline: 1.1569x; 1.1569x over previous
//
#include <hip/hip_runtime.h>
#include <hip/hip_bf16.h>

typedef _Float16 h2 __attribute__((ext_vector_type(2)));
typedef _Float16 h8 __attribute__((ext_vector_type(8)));
typedef __attribute__((ext_vector_type(8))) unsigned short ushort8v;
typedef __attribute__((ext_vector_type(4))) float f32x4;

__device__ __forceinline__ unsigned short f2h_bits(float f) {
    union { _Float16 h; unsigned short u; } v;
    v.h = (_Float16)f;
    return v.u;
}

// prep: blocks [0,64)          -> W1/W2 permute to MFMA-fragment-linear fp16
//       blocks [64,64+nxb)     -> x (f32) -> xh (fp16), 8 elems/thread
//       blocks [64+nxb, ...)   -> degree histogram into offs + rank[e]
__global__ __launch_bounds__(256) void prep_kernel(
    const float* __restrict__ W1, const float* __restrict__ W2,
    const float* __restrict__ x, const int* __restrict__ dst,
    unsigned short* __restrict__ wtf1, unsigned short* __restrict__ wtf2,
    unsigned short* __restrict__ xh, int* __restrict__ offs,
    int* __restrict__ rank, int n8, int E, int nxb)
{
    int bid = blockIdx.x;
    if (bid < 64) {
        int t = bid * 256 + threadIdx.x;   // 0..16383
        int k = t >> 7, j = t & 127;
        int jt = j >> 4, r = j & 15, kt = k >> 5, kg = (k >> 3) & 3, e = k & 7;
        int flin = (jt * 4 + kt) * 512 + (kg * 16 + r) * 8 + e;
        wtf1[flin] = f2h_bits(W1[t]);
        wtf2[flin] = f2h_bits(W2[t]);
        return;
    }
    if (bid < 64 + nxb) {
        int t = (bid - 64) * 256 + threadIdx.x;
        if (t >= n8) return;
        float4 x0 = reinterpret_cast<const float4*>(x)[(size_t)t * 2];
        float4 x1 = reinterpret_cast<const float4*>(x)[(size_t)t * 2 + 1];
        ushort8v o;
        o[0] = f2h_bits(x0.x); o[1] = f2h_bits(x0.y);
        o[2] = f2h_bits(x0.z); o[3] = f2h_bits(x0.w);
        o[4] = f2h_bits(x1.x); o[5] = f2h_bits(x1.y);
        o[6] = f2h_bits(x1.z); o[7] = f2h_bits(x1.w);
        reinterpret_cast<ushort8v*>(xh)[t] = o;
        return;
    }
    int e = (bid - 64 - nxb) * 256 + threadIdx.x;
    if (e < E) rank[e] = atomicAdd(&offs[dst[e]], 1);
}

// Per-1024-chunk exclusive scan in place; LAST finishing block scans chunk sums.
__global__ __launch_bounds__(256) void scan_kernel(
    int* __restrict__ offs, int* __restrict__ bsums, int* __restrict__ done,
    int N, int nchunk)
{
    __shared__ int tsum[256];
    __shared__ int amLast;
    int c = blockIdx.x, tid = threadIdx.x;
    int base = c * 1024 + tid * 4;
    int v[4]; int tl = 0;
    #pragma unroll
    for (int j = 0; j < 4; ++j) {
        v[j] = (base + j < N) ? offs[base + j] : 0;
        tl += v[j];
    }
    tsum[tid] = tl; __syncthreads();
    for (int off = 1; off < 256; off <<= 1) {
        int u = (tid >= off) ? tsum[tid - off] : 0;
        __syncthreads();
        tsum[tid] += u;
        __syncthreads();
    }
    int run = tsum[tid] - tl;   // exclusive within chunk
    #pragma unroll
    for (int j = 0; j < 4; ++j) {
        if (base + j < N) offs[base + j] = run;
        run += v[j];
    }
    if (tid == 255) {
        __hip_atomic_store(&bsums[c], tsum[255], __ATOMIC_RELEASE,
                           __HIP_MEMORY_SCOPE_AGENT);
        int prev = __hip_atomic_fetch_add(done, 1, __ATOMIC_ACQ_REL,
                                          __HIP_MEMORY_SCOPE_AGENT);
        amLast = (prev == nchunk - 1);
    }
    __syncthreads();
    if (amLast) {
        int bv = (tid < nchunk)
            ? __hip_atomic_load(&bsums[tid], __ATOMIC_ACQUIRE,
                                __HIP_MEMORY_SCOPE_AGENT) : 0;
        tsum[tid] = bv; __syncthreads();
        for (int off = 1; off < 256; off <<= 1) {
            int u = (tid >= off) ? tsum[tid - off] : 0;
            __syncthreads();
            tsum[tid] += u;
            __syncthreads();
        }
        if (tid < nchunk)
            __hip_atomic_store(&bsums[tid], tsum[tid] - bv, __ATOMIC_RELEASE,
                               __HIP_MEMORY_SCOPE_AGENT);
    }
}

// Scatter (src, {w,w} fp16-pair) into CSR slot offs[d]+bsums+rank — NO atomic.
__global__ __launch_bounds__(256) void scatter_kernel(
    const int* __restrict__ src, const int* __restrict__ dst,
    const float* __restrict__ ew, const int* __restrict__ offs,
    const int* __restrict__ bsums, const int* __restrict__ rank,
    int2* __restrict__ esrt, int E)
{
    int e = blockIdx.x * 256 + threadIdx.x;
    if (e >= E) return;
    int d = dst[e];
    int pos = offs[d] + bsums[d >> 10] + rank[e];
    _Float16 wh = (_Float16)ew[e];
    union { h2 h; int i; } uw; uw.h = (h2){wh, wh};
    esrt[pos] = make_int2(src[e], uw.i);
}

// ---- Fused: CSR gather -> LDS -> 2x f16 MFMA. 128 thr / 32 nodes / 8KB LDS.
// (128,4): VGPR cap 128 — R11's (128,8)=64-VGPR cap caused scratch spills
// (VGPR_Count 32, WRITE_SIZE doubled). Small blocks raise resident blocks/CU.
__global__ __launch_bounds__(128, 4) void fused_kernel(
    const unsigned short* __restrict__ xh, const int* __restrict__ offs,
    const int* __restrict__ bsums, const int2* __restrict__ esrt,
    const unsigned short* __restrict__ wtf1,
    const unsigned short* __restrict__ wtf2,
    const float* __restrict__ b1, const float* __restrict__ b2,
    float* __restrict__ y, int N, int E)
{
    __shared__ __align__(16) unsigned short Hs[32 * 128];
    int tid = threadIdx.x;
    int node0 = blockIdx.x * 32;

    // Phase 1: gather. 8 groups x 16 lanes; group g owns rows {g, 8+g, 16+g, 24+g}.
    // Lane l holds elems 8l..8l+7 (16B -> 256B/row coalesced per broadcast src).
    {
        int g = tid >> 4, l = tid & 15;
        const h8* xr = reinterpret_cast<const h8*>(xh);

        // Prefetch 4 node-streams' CSR ranges, batch-0 metadata, self rows.
        int sA[4], eA[4];
        #pragma unroll
        for (int it = 0; it < 4; ++it) {
            int node = node0 + it * 8 + g;
            int nn = (node < N) ? node : N - 1;
            sA[it] = offs[nn] + bsums[nn >> 10];
            int np = nn + 1;
            eA[it] = (np == N) ? E : offs[np] + bsums[np >> 10];
        }
        int2 evA[4];
        h8 selfA[4];
        #pragma unroll
        for (int it = 0; it < 4; ++it) {
            evA[it] = make_int2(0, 0);
            if (sA[it] + l < eA[it]) evA[it] = esrt[sA[it] + l];
            int node = node0 + it * 8 + g;
            int nn = (node < N) ? node : N - 1;
            selfA[it] = xr[(size_t)nn * 16 + l];
        }

        #pragma unroll
        for (int it = 0; it < 4; ++it) {
            int m = it * 8 + g;
            int node = node0 + m;
            h8 acc = (h8)(_Float16)0;
            if (node < N) {
                acc = selfA[it];                   // self-term (EPS=0)
                int s = sA[it], e = eA[it];
                int2 ev = evA[it];
                for (int base = s; base < e; base += 16) {
                    int cnt = min(e - base, 16);
                    for (int j = 0; j < cnt; j += 8) {
                        h8 v[8]; int wb[8];
                        #pragma unroll
                        for (int q = 0; q < 8; ++q) {
                            int sq = __shfl(ev.x, j + q, 16);
                            wb[q]  = __shfl(ev.y, j + q, 16);
                            v[q] = xr[(size_t)sq * 16 + l];
                        }
                        #pragma unroll
                        for (int q = 0; q < 8; ++q) {
                            union { int4 i; h8 h; } uw;
                            uw.i = make_int4(wb[q], wb[q], wb[q], wb[q]);
                            acc += uw.h * v[q];    // 4x v_pk_fma_f16
                        }
                    }
                    // next batch's metadata (rare: deg > 16)
                    ev = make_int2(0, 0);
                    if (base + 16 + l < e) ev = esrt[base + 16 + l];
                }
            }
            // lane l holds chunk l (8 elems); swizzled chunk slot l ^ (m&7)
            int soff = m * 128 + ((l ^ (m & 7)) << 3);
            *reinterpret_cast<h8*>(&Hs[soff]) = acc;
        }
    }
    __syncthreads();

    int wave = tid >> 6, lane = tid & 63;   // wave in {0,1}
    int r = lane & 15, kg = lane >> 4;
    int row0 = node0 + wave * 16;
    int mr = wave * 16 + r;

    h8 a[4];
    #pragma unroll
    for (int kt = 0; kt < 4; ++kt)
        a[kt] = *reinterpret_cast<const h8*>(
            &Hs[mr * 128 + (((kt * 4 + kg) ^ (r & 7)) << 3)]);

    f32x4 acc1[8];
    #pragma unroll
    for (int jt = 0; jt < 8; ++jt) acc1[jt] = {0.f, 0.f, 0.f, 0.f};

    #pragma unroll
    for (int jt = 0; jt < 8; ++jt) {
        #pragma unroll
        for (int kt = 0; kt < 4; ++kt) {
            h8 b = *reinterpret_cast<const h8*>(
                wtf1 + ((jt * 4 + kt) << 9) + (lane << 3));   // coalesced
            acc1[jt] = __builtin_amdgcn_mfma_f32_16x16x32_f16(a[kt], b, acc1[jt], 0, 0, 0);
        }
    }

    #pragma unroll
    for (int jt = 0; jt < 8; ++jt) {
        float bias = b1[jt * 16 + r];
        int col = jt * 16 + r;
        #pragma unroll
        for (int reg = 0; reg < 4; ++reg) {
            int m2 = wave * 16 + kg * 4 + reg;
            float h = fmaxf(acc1[jt][reg] + bias, 0.0f);
            Hs[m2 * 128 + (((col >> 3) ^ (m2 & 7)) << 3) + (col & 7)] = f2h_bits(h);
        }
    }
    __syncthreads();

    h8 a2[4];
    #pragma unroll
    for (int kt = 0; kt < 4; ++kt)
        a2[kt] = *reinterpret_cast<const h8*>(
            &Hs[mr * 128 + (((kt * 4 + kg) ^ (r & 7)) << 3)]);

    f32x4 acc2[8];
    #pragma unroll
    for (int jt = 0; jt < 8; ++jt) acc2[jt] = {0.f, 0.f, 0.f, 0.f};

    #pragma unroll
    for (int jt = 0; jt < 8; ++jt) {
        #pragma unroll
        for (int kt = 0; kt < 4; ++kt) {
            h8 b = *reinterpret_cast<const h8*>(
                wtf2 + ((jt * 4 + kt) << 9) + (lane << 3));
            acc2[jt] = __builtin_amdgcn_mfma_f32_16x16x32_f16(a2[kt], b, acc2[jt], 0, 0, 0);
        }
    }

    #pragma unroll
    for (int jt = 0; jt < 8; ++jt) {
        float bias = b2[jt * 16 + r];
        #pragma unroll
        for (int reg = 0; reg < 4; ++reg) {
            int orow = row0 + kg * 4 + reg;
            if (orow < N)
                y[(size_t)orow * 128 + jt * 16 + r] = acc2[jt][reg] + bias;
        }
    }
}

extern "C" void kernel_launch(void* const* d_in, const int* in_sizes, int n_in,
                              void* d_out, int out_size, void* d_ws, size_t ws_size,
                              hipStream_t stream) {
    const float* x  = (const float*)d_in[0];
    const int*   ei = (const int*)d_in[1];      // [2,E] as int32
    const float* ew = (const float*)d_in[2];
    const float* W1 = (const float*)d_in[3];
    const float* b1 = (const float*)d_in[4];
    const float* W2 = (const float*)d_in[5];
    const float* b2 = (const float*)d_in[6];
    float* y = (float*)d_out;

    int N = in_sizes[0] / 128;   // 100000
    int E = in_sizes[2];         // 600000
    const size_t ND = (size_t)N * 128;
    int nchunk = (N + 1023) / 1024;   // 98
    int n8 = (int)(ND / 8);
    int nxb = (n8 + 255) / 256;
    int nhist = (E + 255) / 256;

    char* ws = (char*)d_ws;
    size_t off = 0;
    auto bump = [&](size_t bytes) {
        void* p = ws + off;
        off += (bytes + 255) & ~(size_t)255;
        return p;
    };
    // zero-region first (one memset covers offs, done)
    size_t zstart = off;
    int*            offs   = (int*)bump((size_t)N * 4);
    int*            done   = (int*)bump(256);
    size_t zbytes = off - zstart;
    int*            bsums  = (int*)bump(1024);
    int*            rank   = (int*)bump((size_t)E * 4);
    unsigned short* wtf1   = (unsigned short*)bump(128 * 128 * 2);
    unsigned short* wtf2   = (unsigned short*)bump(128 * 128 * 2);
    unsigned short* xh     = (unsigned short*)bump(ND * 2);          // 25.6 MB
    int2*           esrt   = (int2*)bump((size_t)E * 8);

    const int* src = ei;
    const int* dst = ei + E;

    hipMemsetAsync(ws + zstart, 0, zbytes, stream);
    prep_kernel<<<64 + nxb + nhist, 256, 0, stream>>>(
        W1, W2, x, dst, wtf1, wtf2, xh, offs, rank, n8, E, nxb);
    scan_kernel<<<nchunk, 256, 0, stream>>>(offs, bsums, done, N, nchunk);
    scatter_kernel<<<nhist, 256, 0, stream>>>(src, dst, ew, offs, bsums,
                                              rank, esrt, E);
    fused_kernel<<<(N + 31) / 32, 128, 0, stream>>>(
        xh, offs, bsums, esrt, wtf1, wtf2, b1, b2, y, N, E);
}

// Round 13
// 105.832 us; speedup vs baseline: 1.2572x; 1.0867x over previous
//
#include <hip/hip_runtime.h>
#include <hip/hip_bf16.h>

#define CAP 32          // per-node bucket capacity (Poisson(6): P(deg>32) ~ 1e-12)
#define OVF_MAX 4096

typedef _Float16 h2 __attribute__((ext_vector_type(2)));
typedef _Float16 h8 __attribute__((ext_vector_type(8)));
typedef __attribute__((ext_vector_type(8))) unsigned short ushort8v;
typedef __attribute__((ext_vector_type(4))) float f32x4;

__device__ __forceinline__ unsigned short f2h_bits(float f) {
    union { _Float16 h; unsigned short u; } v;
    v.h = (_Float16)f;
    return v.u;
}

// prep: blocks [0,64)       -> W1/W2 permute to MFMA-fragment-linear fp16
//       blocks [64,64+nxb)  -> x (f32) -> xh (fp16), 8 elems/thread
//       blocks [64+nxb,...) -> count + DIRECT bucket scatter (no scan needed):
//                              rank = atomicAdd(cnt[dst]); esrt[dst*CAP+rank]=(src,w)
__global__ __launch_bounds__(256) void prep_kernel(
    const float* __restrict__ W1, const float* __restrict__ W2,
    const float* __restrict__ x,
    const int* __restrict__ src, const int* __restrict__ dst,
    const float* __restrict__ ew,
    unsigned short* __restrict__ wtf1, unsigned short* __restrict__ wtf2,
    unsigned short* __restrict__ xh, int* __restrict__ cnt,
    int2* __restrict__ esrt, int4* __restrict__ ovf, int* __restrict__ ovf_cnt,
    int n8, int E, int nxb)
{
    int bid = blockIdx.x;
    if (bid < 64) {
        int t = bid * 256 + threadIdx.x;   // 0..16383
        int k = t >> 7, j = t & 127;
        int jt = j >> 4, r = j & 15, kt = k >> 5, kg = (k >> 3) & 3, e = k & 7;
        int flin = (jt * 4 + kt) * 512 + (kg * 16 + r) * 8 + e;
        wtf1[flin] = f2h_bits(W1[t]);
        wtf2[flin] = f2h_bits(W2[t]);
        return;
    }
    if (bid < 64 + nxb) {
        int t = (bid - 64) * 256 + threadIdx.x;
        if (t >= n8) return;
        float4 x0 = reinterpret_cast<const float4*>(x)[(size_t)t * 2];
        float4 x1 = reinterpret_cast<const float4*>(x)[(size_t)t * 2 + 1];
        ushort8v o;
        o[0] = f2h_bits(x0.x); o[1] = f2h_bits(x0.y);
        o[2] = f2h_bits(x0.z); o[3] = f2h_bits(x0.w);
        o[4] = f2h_bits(x1.x); o[5] = f2h_bits(x1.y);
        o[6] = f2h_bits(x1.z); o[7] = f2h_bits(x1.w);
        reinterpret_cast<ushort8v*>(xh)[t] = o;
        return;
    }
    int e = (bid - 64 - nxb) * 256 + threadIdx.x;
    if (e >= E) return;
    int d = dst[e];
    int r = atomicAdd(&cnt[d], 1);
    _Float16 wh = (_Float16)ew[e];
    union { h2 h; int i; } uw; uw.h = (h2){wh, wh};
    int2 rec = make_int2(src[e], uw.i);
    if (r < CAP) {
        esrt[(size_t)d * CAP + r] = rec;
    } else {
        int o = atomicAdd(ovf_cnt, 1);
        if (o < OVF_MAX) ovf[o] = make_int4(d, rec.x, rec.y, 0);
    }
}

// ---- Fused: bucket gather -> LDS -> 2x f16 MFMA. 128 thr / 32 nodes / 8KB LDS.
__global__ __launch_bounds__(128, 4) void fused_kernel(
    const unsigned short* __restrict__ xh, const int* __restrict__ cnt,
    const int2* __restrict__ esrt,
    const int4* __restrict__ ovf, const int* __restrict__ ovf_cnt,
    const unsigned short* __restrict__ wtf1,
    const unsigned short* __restrict__ wtf2,
    const float* __restrict__ b1, const float* __restrict__ b2,
    float* __restrict__ y, int N)
{
    __shared__ __align__(16) unsigned short Hs[32 * 128];
    int tid = threadIdx.x;
    int node0 = blockIdx.x * 32;
    int ovfc = *ovf_cnt;   // ~always 0; uniform L2-hit load

    // Phase 1: gather. 8 groups x 16 lanes; group g owns rows {g, 8+g, 16+g, 24+g}.
    // Lane l holds elems 8l..8l+7 (16B -> 256B/row per broadcast src).
    {
        int g = tid >> 4, l = tid & 15;
        const h8* xr = reinterpret_cast<const h8*>(xh);

        int degA[4];
        #pragma unroll
        for (int it = 0; it < 4; ++it) {
            int node = node0 + it * 8 + g;
            int nn = (node < N) ? node : N - 1;
            degA[it] = cnt[nn];
        }
        int2 evA[4];
        h8 selfA[4];
        #pragma unroll
        for (int it = 0; it < 4; ++it) {
            int node = node0 + it * 8 + g;
            int nn = (node < N) ? node : N - 1;
            evA[it] = make_int2(0, 0);
            if (l < min(degA[it], CAP)) evA[it] = esrt[(size_t)nn * CAP + l];
            selfA[it] = xr[(size_t)nn * 16 + l];
        }

        #pragma unroll
        for (int it = 0; it < 4; ++it) {
            int m = it * 8 + g;
            int node = node0 + m;
            int nn = (node < N) ? node : N - 1;
            h8 acc = selfA[it];                    // self-term (EPS=0)
            int deg = min(degA[it], CAP);
            int2 ev = evA[it];
            for (int base = 0; base < deg; base += 16) {
                int cnt2 = min(deg - base, 16);
                for (int j = 0; j < cnt2; j += 8) {
                    h8 v[8]; int wb[8];
                    #pragma unroll
                    for (int q = 0; q < 8; ++q) {
                        int sq = __shfl(ev.x, j + q, 16);
                        wb[q]  = __shfl(ev.y, j + q, 16);
                        v[q] = xr[(size_t)sq * 16 + l];
                    }
                    #pragma unroll
                    for (int q = 0; q < 8; ++q) {
                        union { int4 i; h8 h; } uw;
                        uw.i = make_int4(wb[q], wb[q], wb[q], wb[q]);
                        acc += uw.h * v[q];        // 4x v_pk_fma_f16 (pads w=0)
                    }
                }
                // next 16-batch metadata (deg in (16,32])
                ev = make_int2(0, 0);
                if (base + 16 + l < deg) ev = esrt[(size_t)nn * CAP + base + 16 + l];
            }
            // exact overflow path (deg > CAP): scan tiny COO list
            if (ovfc > 0 && degA[it] > CAP && node < N) {
                for (int o = 0; o < ovfc && o < OVF_MAX; ++o) {
                    int4 t4 = ovf[o];
                    if (t4.x == node) {
                        union { int4 i; h8 h; } uw;
                        uw.i = make_int4(t4.z, t4.z, t4.z, t4.z);
                        acc += uw.h * xr[(size_t)t4.y * 16 + l];
                    }
                }
            }
            // lane l holds chunk l (8 elems); swizzled chunk slot l ^ (m&7)
            int soff = m * 128 + ((l ^ (m & 7)) << 3);
            *reinterpret_cast<h8*>(&Hs[soff]) = acc;
        }
    }
    __syncthreads();

    int wave = tid >> 6, lane = tid & 63;   // wave in {0,1}
    int r = lane & 15, kg = lane >> 4;
    int row0 = node0 + wave * 16;
    int mr = wave * 16 + r;

    h8 a[4];
    #pragma unroll
    for (int kt = 0; kt < 4; ++kt)
        a[kt] = *reinterpret_cast<const h8*>(
            &Hs[mr * 128 + (((kt * 4 + kg) ^ (r & 7)) << 3)]);

    f32x4 acc1[8];
    #pragma unroll
    for (int jt = 0; jt < 8; ++jt) acc1[jt] = {0.f, 0.f, 0.f, 0.f};

    #pragma unroll
    for (int jt = 0; jt < 8; ++jt) {
        #pragma unroll
        for (int kt = 0; kt < 4; ++kt) {
            h8 b = *reinterpret_cast<const h8*>(
                wtf1 + ((jt * 4 + kt) << 9) + (lane << 3));   // coalesced
            acc1[jt] = __builtin_amdgcn_mfma_f32_16x16x32_f16(a[kt], b, acc1[jt], 0, 0, 0);
        }
    }

    #pragma unroll
    for (int jt = 0; jt < 8; ++jt) {
        float bias = b1[jt * 16 + r];
        int col = jt * 16 + r;
        #pragma unroll
        for (int reg = 0; reg < 4; ++reg) {
            int m2 = wave * 16 + kg * 4 + reg;
            float h = fmaxf(acc1[jt][reg] + bias, 0.0f);
            Hs[m2 * 128 + (((col >> 3) ^ (m2 & 7)) << 3) + (col & 7)] = f2h_bits(h);
        }
    }
    __syncthreads();

    h8 a2[4];
    #pragma unroll
    for (int kt = 0; kt < 4; ++kt)
        a2[kt] = *reinterpret_cast<const h8*>(
            &Hs[mr * 128 + (((kt * 4 + kg) ^ (r & 7)) << 3)]);

    f32x4 acc2[8];
    #pragma unroll
    for (int jt = 0; jt < 8; ++jt) acc2[jt] = {0.f, 0.f, 0.f, 0.f};

    #pragma unroll
    for (int jt = 0; jt < 8; ++jt) {
        #pragma unroll
        for (int kt = 0; kt < 4; ++kt) {
            h8 b = *reinterpret_cast<const h8*>(
                wtf2 + ((jt * 4 + kt) << 9) + (lane << 3));
            acc2[jt] = __builtin_amdgcn_mfma_f32_16x16x32_f16(a2[kt], b, acc2[jt], 0, 0, 0);
        }
    }

    #pragma unroll
    for (int jt = 0; jt < 8; ++jt) {
        float bias = b2[jt * 16 + r];
        #pragma unroll
        for (int reg = 0; reg < 4; ++reg) {
            int orow = row0 + kg * 4 + reg;
            if (orow < N)
                y[(size_t)orow * 128 + jt * 16 + r] = acc2[jt][reg] + bias;
        }
    }
}

extern "C" void kernel_launch(void* const* d_in, const int* in_sizes, int n_in,
                              void* d_out, int out_size, void* d_ws, size_t ws_size,
                              hipStream_t stream) {
    const float* x  = (const float*)d_in[0];
    const int*   ei = (const int*)d_in[1];      // [2,E] as int32
    const float* ew = (const float*)d_in[2];
    const float* W1 = (const float*)d_in[3];
    const float* b1 = (const float*)d_in[4];
    const float* W2 = (const float*)d_in[5];
    const float* b2 = (const float*)d_in[6];
    float* y = (float*)d_out;

    int N = in_sizes[0] / 128;   // 100000
    int E = in_sizes[2];         // 600000
    const size_t ND = (size_t)N * 128;
    int n8 = (int)(ND / 8);
    int nxb = (n8 + 255) / 256;
    int nhist = (E + 255) / 256;

    char* ws = (char*)d_ws;
    size_t off = 0;
    auto bump = [&](size_t bytes) {
        void* p = ws + off;
        off += (bytes + 255) & ~(size_t)255;
        return p;
    };
    // zero-region first (one memset covers cnt + ovf_cnt)
    size_t zstart = off;
    int*            cnt     = (int*)bump((size_t)N * 4);
    int*            ovf_cnt = (int*)bump(256);
    size_t zbytes = off - zstart;
    unsigned short* wtf1    = (unsigned short*)bump(128 * 128 * 2);
    unsigned short* wtf2    = (unsigned short*)bump(128 * 128 * 2);
    unsigned short* xh      = (unsigned short*)bump(ND * 2);           // 25.6 MB
    int2*           esrt    = (int2*)bump((size_t)N * CAP * 8);        // 25.6 MB
    int4*           ovf     = (int4*)bump((size_t)OVF_MAX * 16);       // 64 KB

    const int* src = ei;
    const int* dst = ei + E;

    hipMemsetAsync(ws + zstart, 0, zbytes, stream);
    prep_kernel<<<64 + nxb + nhist, 256, 0, stream>>>(
        W1, W2, x, src, dst, ew, wtf1, wtf2, xh, cnt, esrt, ovf, ovf_cnt,
        n8, E, nxb);
    fused_kernel<<<(N + 31) / 32, 128, 0, stream>>>(
        xh, cnt, esrt, ovf, ovf_cnt, wtf1, wtf2, b1, b2, y, N);
}